// Round 6
// baseline (101.149 us; speedup 1.0000x reference)
//
#include <hip/hip_runtime.h>

#define NB 4096
#define DK 768
#define SCALE_S 0.5295756522f

typedef float f32x4 __attribute__((ext_vector_type(4)));
typedef __bf16 bf16x8 __attribute__((ext_vector_type(8)));

// ---- ws layout (bytes) ----
#define OFF_XB      0u            // 4096*768 bf16 = 6291456
#define OFF_YB      6291456u
#define OFF_ROWPM   12582912u     // 32*4096 f32 = 524288 per region
#define OFF_ROWPS   13107200u
#define OFF_COLPM   13631488u
#define OFF_COLPS   14155776u
#define OFF_LSER    14680064u     // 4096 f32
#define OFF_LSEC    14696448u
#define OFF_BITS    14712832u     // 4096 u32
#define OFF_CSPART  14729216u     // 16*32 int
#define OFF_DOTP    14731264u     // 96 f32
#define OFF_UPART   14731648u     // 32*32*768 f32
#define OFF_VPART   17877376u     // 32*32*768 f32  (end ~21 MB)

static __device__ __forceinline__ unsigned short f2bf(float f) {
  union { float f; unsigned u; } x; x.f = f;
  unsigned r = x.u + 0x7fffu + ((x.u >> 16) & 1u);   // RNE
  return (unsigned short)(r >> 16);
}

static __device__ __forceinline__ float bf2f(unsigned short h) {
  union { unsigned u; float f; } x; x.u = ((unsigned)h) << 16;
  return x.f;
}

static __device__ __forceinline__ void gload16(const void* g, void* l) {
  __builtin_amdgcn_global_load_lds(
      (const __attribute__((address_space(1))) unsigned int*)g,
      (__attribute__((address_space(3))) unsigned int*)l,
      16, 0, 0);
}

// K1: fused prep. Blocks 0..15: pack label bits + colsum partials.
// Blocks 16..: fp32->bf16 conversion of X and Y (grid-stride).
__global__ void k_prep(const int* __restrict__ labels, unsigned* __restrict__ bits,
                       int* __restrict__ csPart,
                       const float* __restrict__ X, const float* __restrict__ Y,
                       unsigned short* __restrict__ Xb, unsigned short* __restrict__ Yb) {
  int t = threadIdx.x;
  if (blockIdx.x < 16) {
    __shared__ int cs[32];
    if (t < 32) cs[t] = 0;
    __syncthreads();
    int i = blockIdx.x * 256 + t;
    const int* row = labels + (size_t)i * 32;
    unsigned b = 0;
#pragma unroll
    for (int j = 0; j < 32; ++j) if (row[j] != 0) b |= (1u << j);
    bits[i] = b;
#pragma unroll
    for (int j = 0; j < 32; ++j) if (b & (1u << j)) atomicAdd(&cs[j], 1);
    __syncthreads();
    if (t < 32) csPart[blockIdx.x * 32 + t] = cs[t];
  } else {
    const int N4 = (NB * DK) / 4;  // 786432
    const int stride = (gridDim.x - 16) * 256;
    for (int idx = (blockIdx.x - 16) * 256 + t; idx < 2 * N4; idx += stride) {
      float4 v; unsigned short* dst;
      if (idx < N4) { v = ((const float4*)X)[idx]; dst = Xb + (size_t)idx * 4; }
      else          { v = ((const float4*)Y)[idx - N4]; dst = Yb + (size_t)(idx - N4) * 4; }
      uint2 p;
      p.x = (unsigned)f2bf(v.x) | ((unsigned)f2bf(v.y) << 16);
      p.y = (unsigned)f2bf(v.z) | ((unsigned)f2bf(v.w) << 16);
      *(uint2*)dst = p;
    }
  }
}

// K3: partial U = mask^T X, V = mask^T Y per 128-row chunk, 8 j's per block
// (8 accumulator pairs = proven non-spilling shape; reads bf16)
__launch_bounds__(256, 2)
__global__ void k_uv(const unsigned short* __restrict__ Xb,
                     const unsigned short* __restrict__ Yb,
                     const unsigned* __restrict__ bits,
                     float* __restrict__ Up, float* __restrict__ Vp) {
  int d = blockIdx.x * 256 + threadIdx.x;   // 0..767
  int chunk = blockIdx.y;                    // 0..31
  int jg = blockIdx.z;                       // 0..3
  float u[8], v[8];
#pragma unroll
  for (int j = 0; j < 8; ++j) { u[j] = 0.f; v[j] = 0.f; }
  int i0 = chunk * 128;
#pragma unroll 4
  for (int ii = 0; ii < 128; ++ii) {
    int i = i0 + ii;
    unsigned b = bits[i] >> (jg * 8);
    float x = bf2f(Xb[(size_t)i * DK + d]);
    float y = bf2f(Yb[(size_t)i * DK + d]);
#pragma unroll
    for (int j = 0; j < 8; ++j) {
      bool m = (b >> j) & 1u;
      u[j] += m ? x : 0.f;
      v[j] += m ? y : 0.f;
    }
  }
  size_t base = (size_t)chunk * (32 * DK) + (size_t)jg * (8 * DK);
#pragma unroll
  for (int j = 0; j < 8; ++j) {
    Up[base + j * DK + d] = u[j];
    Vp[base + j * DK + d] = v[j];
  }
}

// K4: m97-structure 128x128 bf16 MFMA GEMM (proven ~900 TF shape): 4 waves,
// single-buffered 16KB LDS, global_load_lds width-16 staging, 16 MFMA/tile/wave,
// ~3 blocks/CU occupancy does the latency hiding. Fused row/col (max,sumexp)
// epilogue writing 32 partials per row/col.
__launch_bounds__(256)
__global__ void k_gemm(const unsigned short* __restrict__ Xb,
                       const unsigned short* __restrict__ Yb,
                       float* __restrict__ rowPM, float* __restrict__ rowPS,
                       float* __restrict__ colPM, float* __restrict__ colPS) {
  __shared__ unsigned short As[128][32];
  __shared__ unsigned short Bs[128][32];

  const int t = threadIdx.x;             // 0..255
  const int wave = t >> 6, lane = t & 63;
  const int wr = wave >> 1, wc = wave & 1;

  // bijective XCD-aware swizzle: 1024 blocks; each XCD gets an 8rb x 16cb patch
  const int bid = blockIdx.x;
  const int xcd = bid & 7, loc = bid >> 3;          // loc 0..127
  const int rb = (xcd & 3) * 8 + (loc >> 4);        // 0..31
  const int cb = (xcd >> 2) * 16 + (loc & 15);      // 0..31

  // staging: thread t loads 16B; row = t>>2, col8 = (t&3)*8; insn1 = rows 64..127
  const int srow = t >> 2;
  const int scol = (t & 3) * 8;
  const unsigned short* gA = Xb + (size_t)(rb * 128 + srow) * DK + scol;
  const unsigned short* gB = Yb + (size_t)(cb * 128 + srow) * DK + scol;
  unsigned short* la = &As[0][0] + wave * 512;   // wave-uniform LDS base
  unsigned short* lb = &Bs[0][0] + wave * 512;

  f32x4 acc[4][4];
#pragma unroll
  for (int m = 0; m < 4; ++m)
#pragma unroll
    for (int n = 0; n < 4; ++n) acc[m][n] = (f32x4){0.f, 0.f, 0.f, 0.f};

  const int lrow = lane & 15;
  const int kch = (lane >> 4) * 8;

  for (int kt = 0; kt < DK / 32; ++kt) {
    __syncthreads();
    gload16(gA + kt * 32, la);
    gload16(gA + kt * 32 + (size_t)64 * DK, la + 2048);
    gload16(gB + kt * 32, lb);
    gload16(gB + kt * 32 + (size_t)64 * DK, lb + 2048);
    __syncthreads();
    bf16x8 af[4], bf[4];
#pragma unroll
    for (int m = 0; m < 4; ++m) af[m] = *(const bf16x8*)&As[wr * 64 + m * 16 + lrow][kch];
#pragma unroll
    for (int n = 0; n < 4; ++n) bf[n] = *(const bf16x8*)&Bs[wc * 64 + n * 16 + lrow][kch];
    __builtin_amdgcn_s_setprio(1);
#pragma unroll
    for (int m = 0; m < 4; ++m)
#pragma unroll
      for (int n = 0; n < 4; ++n)
        acc[m][n] = __builtin_amdgcn_mfma_f32_16x16x32_bf16(af[m], bf[n], acc[m][n], 0, 0, 0);
    __builtin_amdgcn_s_setprio(0);
  }
  __syncthreads();   // all LDS reads done before reuse as reduction scratch

  // ---- epilogue: per-row / per-col (max, sumexp) over this 128x128 tile ----
  // C/D layout: col = lane&15, row = (lane>>4)*4 + reg  [learn_hip m89/m91]
  float* redM  = (float*)&As[0][0];       // [128][2]
  float* redS  = redM + 256;              // [128][2]
  float* redM2 = redS + 256;              // [128][2]
  float* redS2 = redM2 + 256;             // [128][2]   (4KB total, fits in As)

#pragma unroll
  for (int m = 0; m < 4; ++m) {
#pragma unroll
    for (int r = 0; r < 4; ++r) {
      float v0 = SCALE_S * acc[m][0][r];
      float v1 = SCALE_S * acc[m][1][r];
      float v2 = SCALE_S * acc[m][2][r];
      float v3 = SCALE_S * acc[m][3][r];
      float mx = fmaxf(fmaxf(v0, v1), fmaxf(v2, v3));
#pragma unroll
      for (int off = 1; off < 16; off <<= 1) mx = fmaxf(mx, __shfl_xor(mx, off));
      float sm = __expf(v0 - mx) + __expf(v1 - mx) + __expf(v2 - mx) + __expf(v3 - mx);
#pragma unroll
      for (int off = 1; off < 16; off <<= 1) sm += __shfl_xor(sm, off);
      if ((lane & 15) == 0) {
        int row = wr * 64 + m * 16 + (lane >> 4) * 4 + r;
        redM[row * 2 + wc] = mx; redS[row * 2 + wc] = sm;
      }
    }
  }
#pragma unroll
  for (int n = 0; n < 4; ++n) {
    float mx = -3.0e38f;
#pragma unroll
    for (int m = 0; m < 4; ++m)
#pragma unroll
      for (int r = 0; r < 4; ++r) mx = fmaxf(mx, SCALE_S * acc[m][n][r]);
    mx = fmaxf(mx, __shfl_xor(mx, 16));
    mx = fmaxf(mx, __shfl_xor(mx, 32));
    float sm = 0.f;
#pragma unroll
    for (int m = 0; m < 4; ++m)
#pragma unroll
      for (int r = 0; r < 4; ++r) sm += __expf(SCALE_S * acc[m][n][r] - mx);
    sm += __shfl_xor(sm, 16);
    sm += __shfl_xor(sm, 32);
    if (lane < 16) {
      int col = wc * 64 + n * 16 + lane;
      redM2[col * 2 + wr] = mx; redS2[col * 2 + wr] = sm;
    }
  }
  __syncthreads();
  if (t < 128) {
    float m0 = redM[t * 2 + 0], m1 = redM[t * 2 + 1];
    float M = fmaxf(m0, m1);
    float S = redS[t * 2 + 0] * __expf(m0 - M) + redS[t * 2 + 1] * __expf(m1 - M);
    rowPM[(size_t)cb * NB + rb * 128 + t] = M;
    rowPS[(size_t)cb * NB + rb * 128 + t] = S;
  } else {
    int c = t - 128;
    float m0 = redM2[c * 2 + 0], m1 = redM2[c * 2 + 1];
    float M = fmaxf(m0, m1);
    float S = redS2[c * 2 + 0] * __expf(m0 - M) + redS2[c * 2 + 1] * __expf(m1 - M);
    colPM[(size_t)rb * NB + cb * 128 + c] = M;
    colPS[(size_t)rb * NB + cb * 128 + c] = S;
  }
}

// K5: fused tail: blocks 0..31 combine lse partials (32 each); blocks 32..127 U.V dot
__global__ void k_tail(const float* __restrict__ rowPM, const float* __restrict__ rowPS,
                       const float* __restrict__ colPM, const float* __restrict__ colPS,
                       const float* __restrict__ Up, const float* __restrict__ Vp,
                       float* __restrict__ lse_r, float* __restrict__ lse_c,
                       float* __restrict__ dotPart) {
  int b = blockIdx.x;
  if (b < 32) {
    int g = b * 256 + threadIdx.x;  // 0..8191
    const float* pM; const float* pS; float* out; int i;
    if (g < NB) { pM = rowPM; pS = rowPS; out = lse_r; i = g; }
    else        { pM = colPM; pS = colPS; out = lse_c; i = g - NB; }
    float M = -3.0e38f;
#pragma unroll
    for (int c = 0; c < 32; ++c) M = fmaxf(M, pM[(size_t)c * NB + i]);
    float S = 0.f;
#pragma unroll
    for (int c = 0; c < 32; ++c) S += pS[(size_t)c * NB + i] * __expf(pM[(size_t)c * NB + i] - M);
    out[i] = M + __logf(S);
  } else {
    int e = (b - 32) * 256 + threadIdx.x;  // 0..24575
    float U = 0.f, V = 0.f;
#pragma unroll 8
    for (int c = 0; c < 32; ++c) { U += Up[(size_t)c * 24576 + e]; V += Vp[(size_t)c * 24576 + e]; }
    float p = U * V;
#pragma unroll
    for (int off = 32; off; off >>= 1) p += __shfl_down(p, off);
    __shared__ float red[4];
    if ((threadIdx.x & 63) == 0) red[threadIdx.x >> 6] = p;
    __syncthreads();
    if (threadIdx.x == 0) dotPart[b - 32] = red[0] + red[1] + red[2] + red[3];
  }
}

// K7: finalize scalar loss
__global__ void k_final(const unsigned* __restrict__ bits, const int* __restrict__ csPart,
                        const float* __restrict__ lse_r, const float* __restrict__ lse_c,
                        const float* __restrict__ dotPart, float* __restrict__ out) {
  __shared__ int cs[32];
  __shared__ double red[256];
  int t = threadIdx.x;
  if (t < 32) {
    int s = 0;
    for (int b = 0; b < 16; ++b) s += csPart[b * 32 + t];
    cs[t] = s;
  }
  __syncthreads();
  double acc = 0.0;
  for (int i = t; i < NB; i += 256) {
    unsigned b = bits[i];
    int rw = 0;
#pragma unroll
    for (int j = 0; j < 32; ++j) if (b & (1u << j)) rw += cs[j];
    acc += (double)rw * ((double)lse_r[i] + (double)lse_c[i]);
  }
  if (t < 96) acc -= 2.0 * (double)SCALE_S * (double)dotPart[t];
  red[t] = acc;
  __syncthreads();
  for (int s = 128; s; s >>= 1) {
    if (t < s) red[t] += red[t + s];
    __syncthreads();
  }
  if (t == 0) out[0] = (float)(red[0] / (2.0 * (double)NB * 32.0));
}

extern "C" void kernel_launch(void* const* d_in, const int* in_sizes, int n_in,
                              void* d_out, int out_size, void* d_ws, size_t ws_size,
                              hipStream_t stream) {
  const float* X = (const float*)d_in[0];
  const float* Y = (const float*)d_in[1];
  const int* labels = (const int*)d_in[2];
  char* ws = (char*)d_ws;

  unsigned short* Xb = (unsigned short*)(ws + OFF_XB);
  unsigned short* Yb = (unsigned short*)(ws + OFF_YB);
  float* rowPM = (float*)(ws + OFF_ROWPM);
  float* rowPS = (float*)(ws + OFF_ROWPS);
  float* colPM = (float*)(ws + OFF_COLPM);
  float* colPS = (float*)(ws + OFF_COLPS);
  float* lse_r = (float*)(ws + OFF_LSER);
  float* lse_c = (float*)(ws + OFF_LSEC);
  unsigned* bits = (unsigned*)(ws + OFF_BITS);
  int* csPart = (int*)(ws + OFF_CSPART);
  float* dotPart = (float*)(ws + OFF_DOTP);
  float* Up = (float*)(ws + OFF_UPART);
  float* Vp = (float*)(ws + OFF_VPART);

  k_prep<<<528, 256, 0, stream>>>(labels, bits, csPart, X, Y, Xb, Yb);
  k_uv<<<dim3(3, 32, 4), 256, 0, stream>>>(Xb, Yb, bits, Up, Vp);
  k_gemm<<<1024, 256, 0, stream>>>(Xb, Yb, rowPM, rowPS, colPM, colPS);
  k_tail<<<128, 256, 0, stream>>>(rowPM, rowPS, colPM, colPS, Up, Vp, lse_r, lse_c, dotPart);
  k_final<<<1, 256, 0, stream>>>(bits, csPart, lse_r, lse_c, dotPart, (float*)d_out);
}

// Round 7
// 62.660 us; speedup vs baseline: 1.6142x; 1.6142x over previous
//
#include <hip/hip_runtime.h>

#define NB 4096
#define DK 768
#define SCALE_S 0.5295756522f

typedef float f32x4 __attribute__((ext_vector_type(4)));
typedef __bf16 bf16x8 __attribute__((ext_vector_type(8)));

// ---- ws layout (bytes) ----
#define OFF_XB      0u            // 4096*768 bf16 = 6291456
#define OFF_YB      6291456u
#define OFF_ROWPM   12582912u     // 16*4096 f32 (region reserved 512KB)
#define OFF_ROWPS   13107200u
#define OFF_COLPM   13631488u
#define OFF_COLPS   14155776u
#define OFF_LSER    14680064u     // 4096 f32
#define OFF_LSEC    14696448u
#define OFF_BITS    14712832u     // 4096 u32
#define OFF_CSPART  14729216u     // 16*32 int
#define OFF_DOTP    14731264u     // 256 f32

static __device__ __forceinline__ unsigned short f2bf(float f) {
  union { float f; unsigned u; } x; x.f = f;
  unsigned r = x.u + 0x7fffu + ((x.u >> 16) & 1u);   // RNE
  return (unsigned short)(r >> 16);
}

static __device__ __forceinline__ void gload16(const void* g, void* l) {
  __builtin_amdgcn_global_load_lds(
      (const __attribute__((address_space(1))) unsigned int*)g,
      (__attribute__((address_space(3))) unsigned int*)l,
      16, 0, 0);
}

// K1: fused prep. Blocks 0..15: pack label bits + colsum partials.
// Blocks 16..: fp32->bf16 conversion of X and Y (grid-stride).
__global__ void k_prep(const int* __restrict__ labels, unsigned* __restrict__ bits,
                       int* __restrict__ csPart,
                       const float* __restrict__ X, const float* __restrict__ Y,
                       unsigned short* __restrict__ Xb, unsigned short* __restrict__ Yb) {
  int t = threadIdx.x;
  if (blockIdx.x < 16) {
    __shared__ int cs[32];
    if (t < 32) cs[t] = 0;
    __syncthreads();
    int i = blockIdx.x * 256 + t;
    const int* row = labels + (size_t)i * 32;
    unsigned b = 0;
#pragma unroll
    for (int j = 0; j < 32; ++j) if (row[j] != 0) b |= (1u << j);
    bits[i] = b;
#pragma unroll
    for (int j = 0; j < 32; ++j) if (b & (1u << j)) atomicAdd(&cs[j], 1);
    __syncthreads();
    if (t < 32) csPart[blockIdx.x * 32 + t] = cs[t];
  } else {
    const int N4 = (NB * DK) / 4;  // 786432
    const int stride = (gridDim.x - 16) * 256;
    for (int idx = (blockIdx.x - 16) * 256 + t; idx < 2 * N4; idx += stride) {
      float4 v; unsigned short* dst;
      if (idx < N4) { v = ((const float4*)X)[idx]; dst = Xb + (size_t)idx * 4; }
      else          { v = ((const float4*)Y)[idx - N4]; dst = Yb + (size_t)(idx - N4) * 4; }
      uint2 p;
      p.x = (unsigned)f2bf(v.x) | ((unsigned)f2bf(v.y) << 16);
      p.y = (unsigned)f2bf(v.z) | ((unsigned)f2bf(v.w) << 16);
      *(uint2*)dst = p;
    }
  }
}

// K4: 256x256 bf16 MFMA GEMM (R5 structure: BK=32, 4-slot LDS depth-3 prefetch,
// one barrier per K-tile, counted vmcnt, compiler-scheduled body, setprio).
// Fused epilogue: (a) per-row/per-col (max,sumexp) partials, (b) W.C tile sum
// via popcount(bits_r & bits_c) * C — replaces the former k_uv/U.V-dot kernels.

#define STAGE_A(kt2) do { \
    const int _ss = (kt2) & 3; \
    const unsigned short* _g = gA + (size_t)(kt2) * 32; \
    gload16(_g,                    lds_us + _ss * 16384 + wave * 512); \
    gload16(_g + (size_t)128 * DK, lds_us + _ss * 16384 + 4096 + wave * 512); \
  } while (0)

#define STAGE_B(kt2) do { \
    const int _ss = (kt2) & 3; \
    const unsigned short* _g = gB + (size_t)(kt2) * 32; \
    gload16(_g,                    lds_us + _ss * 16384 + 8192 + wave * 512); \
    gload16(_g + (size_t)128 * DK, lds_us + _ss * 16384 + 12288 + wave * 512); \
  } while (0)

#define BODY(kt1, DOSTAGE) do { \
    asm volatile("" ::: "memory"); \
    if (DOSTAGE) { STAGE_A((kt1) + 3); STAGE_B((kt1) + 3); } \
    const unsigned short* _sb = lds_us + ((kt1) & 3) * 16384; \
    bf16x8 _af[8], _bf[4]; \
    _Pragma("unroll") for (int m = 0; m < 8; ++m) _af[m] = *(const bf16x8*)(_sb + aoff + m * 512); \
    _Pragma("unroll") for (int n = 0; n < 4; ++n) _bf[n] = *(const bf16x8*)(_sb + boff + n * 512); \
    __builtin_amdgcn_s_setprio(1); \
    _Pragma("unroll") for (int m = 0; m < 8; ++m) \
      _Pragma("unroll") for (int n = 0; n < 4; ++n) \
        acc[m][n] = __builtin_amdgcn_mfma_f32_16x16x32_bf16(_af[m], _bf[n], acc[m][n], 0, 0, 0); \
    __builtin_amdgcn_s_setprio(0); \
    asm volatile("" ::: "memory"); \
  } while (0)

__launch_bounds__(512, 2)
__global__ void k_gemm(const unsigned short* __restrict__ Xb,
                       const unsigned short* __restrict__ Yb,
                       const unsigned* __restrict__ bits,
                       float* __restrict__ rowPM, float* __restrict__ rowPS,
                       float* __restrict__ colPM, float* __restrict__ colPS,
                       float* __restrict__ dotPart) {
  extern __shared__ unsigned short lds_us[];

  const int t = threadIdx.x;             // 0..511
  const int wave = t >> 6, lane = t & 63;
  const int wr = wave >> 2, wc = wave & 3;

  // bijective XCD-aware swizzle: each XCD gets a 4rb x 8cb sub-grid
  const int bid = blockIdx.x;
  const int xcd = bid & 7, loc = bid >> 3;
  const int rb = (xcd & 3) * 4 + (loc >> 3);
  const int cb = (xcd >> 2) * 8 + (loc & 7);

  // staging: thread t loads 16B; row = t>>2 (+128/round), 16B col-slot pre-swizzled
  const int srow = t >> 2;
  const int sg = (t & 3) ^ ((t >> 3) & 3);            // inverse swizzle on global source
  const unsigned short* gA = Xb + (size_t)(rb * 256 + srow) * DK + sg * 8;
  const unsigned short* gB = Yb + (size_t)(cb * 256 + srow) * DK + sg * 8;

  // fragment read offsets (shorts), swizzled 16B slot
  const int lrow = lane & 15;
  const int eff8 = ((lane >> 4) ^ ((lrow >> 1) & 3)) * 8;
  const int aoff = (wr * 128 + lrow) * 32 + eff8;          // + m*512, m=0..7
  const int boff = 8192 + (wc * 64 + lrow) * 32 + eff8;    // + n*512, n=0..3

  f32x4 acc[8][4];
#pragma unroll
  for (int m = 0; m < 8; ++m)
#pragma unroll
    for (int n = 0; n < 4; ++n) acc[m][n] = (f32x4){0.f, 0.f, 0.f, 0.f};

  // prologue: stage tiles 0,1,2 (12 loads); wait tile0 (8 outstanding allowed)
  STAGE_A(0); STAGE_B(0); STAGE_A(1); STAGE_B(1); STAGE_A(2); STAGE_B(2);
  asm volatile("s_waitcnt vmcnt(8)" ::: "memory");
  __builtin_amdgcn_s_barrier();

  for (int kt = 0; kt < 21; ++kt) {
    BODY(kt, true);
    asm volatile("s_waitcnt vmcnt(8)" ::: "memory");   // tile kt+1 landed
    __builtin_amdgcn_s_barrier();
  }
  BODY(21, false);
  asm volatile("s_waitcnt vmcnt(4)" ::: "memory");
  __builtin_amdgcn_s_barrier();
  BODY(22, false);
  asm volatile("s_waitcnt vmcnt(0)" ::: "memory");
  __builtin_amdgcn_s_barrier();
  BODY(23, false);
  __syncthreads();   // all LDS reads done before reuse as reduction scratch

  // ---- epilogue ----
  // LDS scratch layout (floats): redM[256][4] | redS[256][4] | redM2[256][2] |
  //   redS2[256][2] | bR[256] u32 | bC[256] u32 | wred[8]
  float* fb    = (float*)lds_us;
  float* redM  = fb;                       // 1024
  float* redS  = fb + 1024;                // 1024
  float* redM2 = fb + 2048;                // 512
  float* redS2 = fb + 2560;                // 512
  unsigned* bR = (unsigned*)(fb + 3072);   // 256
  unsigned* bC = bR + 256;                 // 256
  float* wred  = (float*)(bC + 256);       // 8

  if (t < 256) bR[t] = bits[rb * 256 + t];
  else         bC[t - 256] = bits[cb * 256 + (t - 256)];

  // (a) row partials. C/D layout: col = lane&15, row = (lane>>4)*4 + reg [m89/m91]
#pragma unroll
  for (int m = 0; m < 8; ++m) {
#pragma unroll
    for (int r = 0; r < 4; ++r) {
      float v0 = SCALE_S * acc[m][0][r];
      float v1 = SCALE_S * acc[m][1][r];
      float v2 = SCALE_S * acc[m][2][r];
      float v3 = SCALE_S * acc[m][3][r];
      float mx = fmaxf(fmaxf(v0, v1), fmaxf(v2, v3));
#pragma unroll
      for (int off = 1; off < 16; off <<= 1) mx = fmaxf(mx, __shfl_xor(mx, off));
      float sm = __expf(v0 - mx) + __expf(v1 - mx) + __expf(v2 - mx) + __expf(v3 - mx);
#pragma unroll
      for (int off = 1; off < 16; off <<= 1) sm += __shfl_xor(sm, off);
      if ((lane & 15) == 0) {
        int row = wr * 128 + m * 16 + (lane >> 4) * 4 + r;
        redM[row * 4 + wc] = mx; redS[row * 4 + wc] = sm;
      }
    }
  }
  // col partials
#pragma unroll
  for (int n = 0; n < 4; ++n) {
    float mx = -3.0e38f;
#pragma unroll
    for (int m = 0; m < 8; ++m)
#pragma unroll
      for (int r = 0; r < 4; ++r) mx = fmaxf(mx, SCALE_S * acc[m][n][r]);
    mx = fmaxf(mx, __shfl_xor(mx, 16));
    mx = fmaxf(mx, __shfl_xor(mx, 32));
    float sm = 0.f;
#pragma unroll
    for (int m = 0; m < 8; ++m)
#pragma unroll
      for (int r = 0; r < 4; ++r) sm += __expf(SCALE_S * acc[m][n][r] - mx);
    sm += __shfl_xor(sm, 16);
    sm += __shfl_xor(sm, 32);
    if (lane < 16) {
      int col = wc * 64 + n * 16 + lane;
      redM2[col * 2 + wr] = mx; redS2[col * 2 + wr] = sm;
    }
  }
  __syncthreads();

  // (b) W.C tile sum: ws = sum popcount(bits_row & bits_col) * C  (unscaled C)
  float ws = 0.f;
  {
    unsigned bc[4];
#pragma unroll
    for (int n = 0; n < 4; ++n) bc[n] = bC[wc * 64 + n * 16 + (lane & 15)];
#pragma unroll
    for (int m = 0; m < 8; ++m) {
#pragma unroll
      for (int r = 0; r < 4; ++r) {
        unsigned br = bR[wr * 128 + m * 16 + (lane >> 4) * 4 + r];
#pragma unroll
        for (int n = 0; n < 4; ++n)
          ws += (float)__popc(br & bc[n]) * acc[m][n][r];
      }
    }
  }
#pragma unroll
  for (int off = 32; off; off >>= 1) ws += __shfl_xor(ws, off);
  if (lane == 0) wred[wave] = ws;

  // combine partials -> per-(block,row/col) (M,S)
  if (t < 256) {
    float M = fmaxf(fmaxf(redM[t * 4 + 0], redM[t * 4 + 1]),
                    fmaxf(redM[t * 4 + 2], redM[t * 4 + 3]));
    float S = 0.f;
#pragma unroll
    for (int k = 0; k < 4; ++k) S += redS[t * 4 + k] * __expf(redM[t * 4 + k] - M);
    rowPM[(size_t)cb * NB + rb * 256 + t] = M;
    rowPS[(size_t)cb * NB + rb * 256 + t] = S;
  } else {
    int c = t - 256;
    float m0 = redM2[c * 2 + 0], m1 = redM2[c * 2 + 1];
    float M = fmaxf(m0, m1);
    float S = redS2[c * 2 + 0] * __expf(m0 - M) + redS2[c * 2 + 1] * __expf(m1 - M);
    colPM[(size_t)rb * NB + cb * 256 + c] = M;
    colPS[(size_t)rb * NB + cb * 256 + c] = S;
  }
  __syncthreads();
  if (t == 0) {
    float s = 0.f;
#pragma unroll
    for (int w = 0; w < 8; ++w) s += wred[w];
    dotPart[bid] = s;
  }
}

// K5: combine 16 lse partials per row/col (32 blocks)
__global__ void k_tail(const float* __restrict__ rowPM, const float* __restrict__ rowPS,
                       const float* __restrict__ colPM, const float* __restrict__ colPS,
                       float* __restrict__ lse_r, float* __restrict__ lse_c) {
  int g = blockIdx.x * 256 + threadIdx.x;  // 0..8191
  const float* pM; const float* pS; float* out; int i;
  if (g < NB) { pM = rowPM; pS = rowPS; out = lse_r; i = g; }
  else        { pM = colPM; pS = colPS; out = lse_c; i = g - NB; }
  float M = -3.0e38f;
#pragma unroll
  for (int c = 0; c < 16; ++c) M = fmaxf(M, pM[(size_t)c * NB + i]);
  float S = 0.f;
#pragma unroll
  for (int c = 0; c < 16; ++c) S += pS[(size_t)c * NB + i] * __expf(pM[(size_t)c * NB + i] - M);
  out[i] = M + __logf(S);
}

// K7: finalize scalar loss
__global__ void k_final(const unsigned* __restrict__ bits, const int* __restrict__ csPart,
                        const float* __restrict__ lse_r, const float* __restrict__ lse_c,
                        const float* __restrict__ dotPart, float* __restrict__ out) {
  __shared__ int cs[32];
  __shared__ double red[256];
  int t = threadIdx.x;
  if (t < 32) {
    int s = 0;
    for (int b = 0; b < 16; ++b) s += csPart[b * 32 + t];
    cs[t] = s;
  }
  __syncthreads();
  double acc = 0.0;
  for (int i = t; i < NB; i += 256) {
    unsigned b = bits[i];
    int rw = 0;
#pragma unroll
    for (int j = 0; j < 32; ++j) if (b & (1u << j)) rw += cs[j];
    acc += (double)rw * ((double)lse_r[i] + (double)lse_c[i]);
  }
  acc -= 2.0 * (double)SCALE_S * (double)dotPart[t];   // 256 partials, one per thread
  red[t] = acc;
  __syncthreads();
  for (int s = 128; s; s >>= 1) {
    if (t < s) red[t] += red[t + s];
    __syncthreads();
  }
  if (t == 0) out[0] = (float)(red[0] / (2.0 * (double)NB * 32.0));
}

extern "C" void kernel_launch(void* const* d_in, const int* in_sizes, int n_in,
                              void* d_out, int out_size, void* d_ws, size_t ws_size,
                              hipStream_t stream) {
  const float* X = (const float*)d_in[0];
  const float* Y = (const float*)d_in[1];
  const int* labels = (const int*)d_in[2];
  char* ws = (char*)d_ws;

  unsigned short* Xb = (unsigned short*)(ws + OFF_XB);
  unsigned short* Yb = (unsigned short*)(ws + OFF_YB);
  float* rowPM = (float*)(ws + OFF_ROWPM);
  float* rowPS = (float*)(ws + OFF_ROWPS);
  float* colPM = (float*)(ws + OFF_COLPM);
  float* colPS = (float*)(ws + OFF_COLPS);
  float* lse_r = (float*)(ws + OFF_LSER);
  float* lse_c = (float*)(ws + OFF_LSEC);
  unsigned* bits = (unsigned*)(ws + OFF_BITS);
  int* csPart = (int*)(ws + OFF_CSPART);
  float* dotPart = (float*)(ws + OFF_DOTP);

  // allow 128KB dynamic LDS for k_gemm (idempotent; ignore error)
  (void)hipFuncSetAttribute((const void*)k_gemm,
                            hipFuncAttributeMaxDynamicSharedMemorySize, 131072);

  k_prep<<<528, 256, 0, stream>>>(labels, bits, csPart, X, Y, Xb, Yb);
  k_gemm<<<256, 512, 131072, stream>>>(Xb, Yb, bits, rowPM, rowPS, colPM, colPS, dotPart);
  k_tail<<<32, 256, 0, stream>>>(rowPM, rowPS, colPM, colPS, lse_r, lse_c);
  k_final<<<1, 256, 0, stream>>>(bits, csPart, lse_r, lse_c, dotPart, (float*)d_out);
}

// Round 8
// 57.853 us; speedup vs baseline: 1.7484x; 1.0831x over previous
//
#include <hip/hip_runtime.h>

#define NB 4096
#define DK 768
#define SCALE_S 0.5295756522f

typedef float f32x4 __attribute__((ext_vector_type(4)));
typedef __bf16 bf16x8 __attribute__((ext_vector_type(8)));

// ---- ws layout (bytes) ----
#define OFF_XB      0u            // 4096*768 bf16 = 6291456
#define OFF_YB      6291456u
#define OFF_ROWPM   12582912u     // 16*4096 f32 = 256KB (region 512KB)
#define OFF_ROWPS   13107200u
#define OFF_COLPM   13631488u     // 32*4096 f32 = 512KB
#define OFF_COLPS   14155776u
#define OFF_BITS    14712832u     // 4096 u32
#define OFF_CSPART  14729216u     // 16*32 int
#define OFF_DOTP    14731264u     // 512 f32
#define OFF_WSUM    14733312u     // 32 f32

static __device__ __forceinline__ unsigned short f2bf(float f) {
  union { float f; unsigned u; } x; x.f = f;
  unsigned r = x.u + 0x7fffu + ((x.u >> 16) & 1u);   // RNE
  return (unsigned short)(r >> 16);
}

static __device__ __forceinline__ void gload16(const void* g, void* l) {
  __builtin_amdgcn_global_load_lds(
      (const __attribute__((address_space(1))) unsigned int*)g,
      (__attribute__((address_space(3))) unsigned int*)l,
      16, 0, 0);
}

// K1: fused prep. Blocks 0..15: pack label bits + colsum partials.
// Blocks 16..: fp32->bf16 conversion of X and Y (grid-stride).
__global__ void k_prep(const int* __restrict__ labels, unsigned* __restrict__ bits,
                       int* __restrict__ csPart,
                       const float* __restrict__ X, const float* __restrict__ Y,
                       unsigned short* __restrict__ Xb, unsigned short* __restrict__ Yb) {
  int t = threadIdx.x;
  if (blockIdx.x < 16) {
    __shared__ int cs[32];
    if (t < 32) cs[t] = 0;
    __syncthreads();
    int i = blockIdx.x * 256 + t;
    const int* row = labels + (size_t)i * 32;
    unsigned b = 0;
#pragma unroll
    for (int j = 0; j < 32; ++j) if (row[j] != 0) b |= (1u << j);
    bits[i] = b;
#pragma unroll
    for (int j = 0; j < 32; ++j) if (b & (1u << j)) atomicAdd(&cs[j], 1);
    __syncthreads();
    if (t < 32) csPart[blockIdx.x * 32 + t] = cs[t];
  } else {
    const int N4 = (NB * DK) / 4;  // 786432
    const int stride = (gridDim.x - 16) * 256;
    for (int idx = (blockIdx.x - 16) * 256 + t; idx < 2 * N4; idx += stride) {
      float4 v; unsigned short* dst;
      if (idx < N4) { v = ((const float4*)X)[idx]; dst = Xb + (size_t)idx * 4; }
      else          { v = ((const float4*)Y)[idx - N4]; dst = Yb + (size_t)(idx - N4) * 4; }
      uint2 p;
      p.x = (unsigned)f2bf(v.x) | ((unsigned)f2bf(v.y) << 16);
      p.y = (unsigned)f2bf(v.z) | ((unsigned)f2bf(v.w) << 16);
      *(uint2*)dst = p;
    }
  }
}

// K4: 128x256 bf16 MFMA GEMM. 8 waves (2 row-groups x 4 col-groups), per-wave
// 64x64 out (acc[4][4] = 64 regs -> 4 waves/SIMD), BK=32, 3-slot LDS ring
// (72KB -> 2 blocks/CU), depth-2 prefetch, counted vmcnt(3), setprio.
// Fused epilogue: row/col (max,sumexp) partials + popcount W.C tile sum.
// LDS slot s (shorts, 12288 each): A(128x32) at s*12288, B(256x32) at +4096.

#define STAGE(kt2, ss) do { \
    const unsigned short* _ga = gA + (size_t)(kt2) * 32; \
    const unsigned short* _gb = gB + (size_t)(kt2) * 32; \
    gload16(_ga,                    lds_us + (ss) * 12288 + wave * 512); \
    gload16(_gb,                    lds_us + (ss) * 12288 + 4096 + wave * 512); \
    gload16(_gb + (size_t)128 * DK, lds_us + (ss) * 12288 + 8192 + wave * 512); \
  } while (0)

#define BODY(kt1, DOSTAGE) do { \
    asm volatile("" ::: "memory"); \
    if (DOSTAGE) { STAGE((kt1) + 2, ((kt1) + 2) % 3); } \
    const unsigned short* _sb = lds_us + ((kt1) % 3) * 12288; \
    bf16x8 _af[4], _bf[4]; \
    _Pragma("unroll") for (int m = 0; m < 4; ++m) _af[m] = *(const bf16x8*)(_sb + aoff + m * 512); \
    _Pragma("unroll") for (int n = 0; n < 4; ++n) _bf[n] = *(const bf16x8*)(_sb + 4096 + boff + n * 512); \
    __builtin_amdgcn_s_setprio(1); \
    _Pragma("unroll") for (int m = 0; m < 4; ++m) \
      _Pragma("unroll") for (int n = 0; n < 4; ++n) \
        acc[m][n] = __builtin_amdgcn_mfma_f32_16x16x32_bf16(_af[m], _bf[n], acc[m][n], 0, 0, 0); \
    __builtin_amdgcn_s_setprio(0); \
    asm volatile("" ::: "memory"); \
  } while (0)

__launch_bounds__(512, 4)
__global__ void k_gemm(const unsigned short* __restrict__ Xb,
                       const unsigned short* __restrict__ Yb,
                       const unsigned* __restrict__ bits,
                       float* __restrict__ rowPM, float* __restrict__ rowPS,
                       float* __restrict__ colPM, float* __restrict__ colPS,
                       float* __restrict__ dotPart) {
  extern __shared__ unsigned short lds_us[];

  const int t = threadIdx.x;             // 0..511
  const int wave = t >> 6, lane = t & 63;
  const int wrr = wave >> 2, wcc = wave & 3;   // row-group(2) x col-group(4)

  // bijective XCD-aware swizzle: 512 blocks; each XCD gets an 8rb x 8cb patch
  const int bid = blockIdx.x;
  const int xcd = bid & 7, loc = bid >> 3;          // loc 0..63
  const int rb = (xcd & 3) * 8 + (loc >> 3);        // 0..31
  const int cb = (xcd >> 2) * 8 + (loc & 7);        // 0..15

  // staging: thread t loads 16B; row = t>>2, 16B col-slot pre-swizzled (T2 inverse)
  const int srow = t >> 2;
  const int sg = (t & 3) ^ ((t >> 3) & 3);
  const unsigned short* gA = Xb + (size_t)(rb * 128 + srow) * DK + sg * 8;
  const unsigned short* gB = Yb + (size_t)(cb * 256 + srow) * DK + sg * 8;

  // fragment read offsets (shorts), swizzled 16B chunk
  const int lrow = lane & 15;
  const int eff8 = ((lane >> 4) ^ ((lrow >> 1) & 3)) * 8;
  const int aoff = (wrr * 64 + lrow) * 32 + eff8;   // + m*512, m=0..3
  const int boff = (wcc * 64 + lrow) * 32 + eff8;   // + n*512, n=0..3 (B base +4096)

  f32x4 acc[4][4];
#pragma unroll
  for (int m = 0; m < 4; ++m)
#pragma unroll
    for (int n = 0; n < 4; ++n) acc[m][n] = (f32x4){0.f, 0.f, 0.f, 0.f};

  // prologue: stage tiles 0,1 (6 loads); wait tile0 (3 outstanding allowed)
  STAGE(0, 0); STAGE(1, 1);
  asm volatile("s_waitcnt vmcnt(3)" ::: "memory");
  __builtin_amdgcn_s_barrier();

  for (int kt = 0; kt < 22; ++kt) {        // DK/32 = 24 tiles total
    BODY(kt, true);                         // stages kt+2 into slot (kt+2)%3
    asm volatile("s_waitcnt vmcnt(3)" ::: "memory");   // tile kt+1 landed
    __builtin_amdgcn_s_barrier();
  }
  BODY(22, false);
  asm volatile("s_waitcnt vmcnt(0)" ::: "memory");
  __builtin_amdgcn_s_barrier();
  BODY(23, false);
  __syncthreads();   // all LDS reads done before reuse as reduction scratch

  // ---- epilogue ----
  // LDS scratch (floats): redM[128][4] | redS[128][4] | redM2[256][2] | redS2[256][2]
  //   | bR[128] u32 | bC[256] u32 | wred[8]
  float* fb    = (float*)lds_us;
  float* redM  = fb;                        // 512
  float* redS  = fb + 512;                  // 512
  float* redM2 = fb + 1024;                 // 512
  float* redS2 = fb + 1536;                 // 512
  unsigned* bR = (unsigned*)(fb + 2048);    // 128
  unsigned* bC = bR + 128;                  // 256
  float* wred  = (float*)(bC + 256);        // 8

  if (t < 128) bR[t] = bits[rb * 128 + t];
  else if (t < 384) bC[t - 128] = bits[cb * 256 + (t - 128)];

  // (a) row partials over this wave's 64 cols. C/D: col=lane&15, row=(lane>>4)*4+r
#pragma unroll
  for (int m = 0; m < 4; ++m) {
#pragma unroll
    for (int r = 0; r < 4; ++r) {
      float v0 = SCALE_S * acc[m][0][r];
      float v1 = SCALE_S * acc[m][1][r];
      float v2 = SCALE_S * acc[m][2][r];
      float v3 = SCALE_S * acc[m][3][r];
      float mx = fmaxf(fmaxf(v0, v1), fmaxf(v2, v3));
#pragma unroll
      for (int off = 1; off < 16; off <<= 1) mx = fmaxf(mx, __shfl_xor(mx, off));
      float sm = __expf(v0 - mx) + __expf(v1 - mx) + __expf(v2 - mx) + __expf(v3 - mx);
#pragma unroll
      for (int off = 1; off < 16; off <<= 1) sm += __shfl_xor(sm, off);
      if ((lane & 15) == 0) {
        int row = wrr * 64 + m * 16 + (lane >> 4) * 4 + r;
        redM[row * 4 + wcc] = mx; redS[row * 4 + wcc] = sm;
      }
    }
  }
  // col partials over this wave's 64 rows
#pragma unroll
  for (int n = 0; n < 4; ++n) {
    float mx = -3.0e38f;
#pragma unroll
    for (int m = 0; m < 4; ++m)
#pragma unroll
      for (int r = 0; r < 4; ++r) mx = fmaxf(mx, SCALE_S * acc[m][n][r]);
    mx = fmaxf(mx, __shfl_xor(mx, 16));
    mx = fmaxf(mx, __shfl_xor(mx, 32));
    float sm = 0.f;
#pragma unroll
    for (int m = 0; m < 4; ++m)
#pragma unroll
      for (int r = 0; r < 4; ++r) sm += __expf(SCALE_S * acc[m][n][r] - mx);
    sm += __shfl_xor(sm, 16);
    sm += __shfl_xor(sm, 32);
    if (lane < 16) {
      int col = wcc * 64 + n * 16 + lane;
      redM2[col * 2 + wrr] = mx; redS2[col * 2 + wrr] = sm;
    }
  }
  __syncthreads();

  // (b) W.C tile sum: popcount(bits_row & bits_col) * C (unscaled)
  float ws = 0.f;
  {
    unsigned bc[4];
#pragma unroll
    for (int n = 0; n < 4; ++n) bc[n] = bC[wcc * 64 + n * 16 + (lane & 15)];
#pragma unroll
    for (int m = 0; m < 4; ++m) {
#pragma unroll
      for (int r = 0; r < 4; ++r) {
        unsigned br = bR[wrr * 64 + m * 16 + (lane >> 4) * 4 + r];
#pragma unroll
        for (int n = 0; n < 4; ++n)
          ws += (float)__popc(br & bc[n]) * acc[m][n][r];
      }
    }
  }
#pragma unroll
  for (int off = 32; off; off >>= 1) ws += __shfl_xor(ws, off);
  if (lane == 0) wred[wave] = ws;

  // combine partials -> per-(block,row/col) (M,S)
  if (t < 128) {
    float M = fmaxf(fmaxf(redM[t * 4 + 0], redM[t * 4 + 1]),
                    fmaxf(redM[t * 4 + 2], redM[t * 4 + 3]));
    float S = 0.f;
#pragma unroll
    for (int k = 0; k < 4; ++k) S += redS[t * 4 + k] * __expf(redM[t * 4 + k] - M);
    rowPM[(size_t)cb * NB + rb * 128 + t] = M;
    rowPS[(size_t)cb * NB + rb * 128 + t] = S;
  } else if (t < 384) {
    int c = t - 128;
    float m0 = redM2[c * 2 + 0], m1 = redM2[c * 2 + 1];
    float M = fmaxf(m0, m1);
    float S = redS2[c * 2 + 0] * __expf(m0 - M) + redS2[c * 2 + 1] * __expf(m1 - M);
    colPM[(size_t)rb * NB + cb * 256 + c] = M;
    colPS[(size_t)rb * NB + cb * 256 + c] = S;
  }
  __syncthreads();
  if (t == 0) {
    float s = 0.f;
#pragma unroll
    for (int w = 0; w < 8; ++w) s += wred[w];
    dotPart[bid] = s;
  }
}

// K5: blocks 0..15 rows / 16..31 cols: combine lse partials AND fold in the
// rw-weighted sum (rw = sum_j bit_j * colsum_j) -> one partial per block.
__global__ void k_tail(const float* __restrict__ rowPM, const float* __restrict__ rowPS,
                       const float* __restrict__ colPM, const float* __restrict__ colPS,
                       const unsigned* __restrict__ bits, const int* __restrict__ csPart,
                       float* __restrict__ wsum) {
  __shared__ int cs[32];
  __shared__ float red[256];
  int t = threadIdx.x, b = blockIdx.x;
  if (t < 32) {
    int s = 0;
    for (int k = 0; k < 16; ++k) s += csPart[k * 32 + t];
    cs[t] = s;
  }
  __syncthreads();
  int g = b * 256 + t;   // 0..8191
  int i; float M = -3.0e38f, S = 0.f;
  if (g < NB) {
    i = g;
#pragma unroll
    for (int c = 0; c < 16; ++c) M = fmaxf(M, rowPM[(size_t)c * NB + i]);
#pragma unroll
    for (int c = 0; c < 16; ++c) S += rowPS[(size_t)c * NB + i] * __expf(rowPM[(size_t)c * NB + i] - M);
  } else {
    i = g - NB;
#pragma unroll
    for (int c = 0; c < 32; ++c) M = fmaxf(M, colPM[(size_t)c * NB + i]);
#pragma unroll
    for (int c = 0; c < 32; ++c) S += colPS[(size_t)c * NB + i] * __expf(colPM[(size_t)c * NB + i] - M);
  }
  float lse = M + __logf(S);
  unsigned bb = bits[i];
  int rw = 0;
#pragma unroll
  for (int j = 0; j < 32; ++j) if (bb & (1u << j)) rw += cs[j];
  red[t] = (float)rw * lse;
  __syncthreads();
  for (int s = 128; s; s >>= 1) {
    if (t < s) red[t] += red[t + s];
    __syncthreads();
  }
  if (t == 0) wsum[b] = red[0];
}

// K7: finalize scalar loss from 32 wsum + 512 dot partials
__global__ void k_final(const float* __restrict__ wsum, const float* __restrict__ dotPart,
                        float* __restrict__ out) {
  __shared__ double red[256];
  int t = threadIdx.x;
  double a = 0.0;
  if (t < 32) a += (double)wsum[t];
  a -= 2.0 * (double)SCALE_S * ((double)dotPart[t] + (double)dotPart[t + 256]);
  red[t] = a;
  __syncthreads();
  for (int s = 128; s; s >>= 1) {
    if (t < s) red[t] += red[t + s];
    __syncthreads();
  }
  if (t == 0) out[0] = (float)(red[0] / (2.0 * (double)NB * 32.0));
}

extern "C" void kernel_launch(void* const* d_in, const int* in_sizes, int n_in,
                              void* d_out, int out_size, void* d_ws, size_t ws_size,
                              hipStream_t stream) {
  const float* X = (const float*)d_in[0];
  const float* Y = (const float*)d_in[1];
  const int* labels = (const int*)d_in[2];
  char* ws = (char*)d_ws;

  unsigned short* Xb = (unsigned short*)(ws + OFF_XB);
  unsigned short* Yb = (unsigned short*)(ws + OFF_YB);
  float* rowPM = (float*)(ws + OFF_ROWPM);
  float* rowPS = (float*)(ws + OFF_ROWPS);
  float* colPM = (float*)(ws + OFF_COLPM);
  float* colPS = (float*)(ws + OFF_COLPS);
  unsigned* bits = (unsigned*)(ws + OFF_BITS);
  int* csPart = (int*)(ws + OFF_CSPART);
  float* dotPart = (float*)(ws + OFF_DOTP);
  float* wsum = (float*)(ws + OFF_WSUM);

  // allow 72KB dynamic LDS for k_gemm (idempotent; ignore error)
  (void)hipFuncSetAttribute((const void*)k_gemm,
                            hipFuncAttributeMaxDynamicSharedMemorySize, 73728);

  k_prep<<<528, 256, 0, stream>>>(labels, bits, csPart, X, Y, Xb, Yb);
  k_gemm<<<512, 512, 73728, stream>>>(Xb, Yb, bits, rowPM, rowPS, colPM, colPS, dotPart);
  k_tail<<<32, 256, 0, stream>>>(rowPM, rowPS, colPM, colPS, bits, csPart, wsum);
  k_final<<<1, 256, 0, stream>>>(wsum, dotPart, (float*)d_out);
}

// Round 9
// 55.604 us; speedup vs baseline: 1.8191x; 1.0404x over previous
//
#include <hip/hip_runtime.h>

#define NB 4096
#define DK 768
#define SCALE_S 0.5295756522f

typedef float f32x4 __attribute__((ext_vector_type(4)));
typedef __bf16 bf16x8 __attribute__((ext_vector_type(8)));

// ---- ws layout (bytes) ----
#define OFF_XB      0u            // 4096*768 bf16 = 6291456
#define OFF_YB      6291456u
#define OFF_ROWPM   12582912u     // 16*4096 f32 (region reserved 512KB)
#define OFF_ROWPS   13107200u
#define OFF_COLPM   13631488u
#define OFF_COLPS   14155776u
#define OFF_BITS    14712832u     // 4096 u32
#define OFF_CSPART  14729216u     // 16*32 int
#define OFF_DOTP    14731264u     // 256 f32
#define OFF_WSUM    14732288u     // 32 f32

static __device__ __forceinline__ unsigned short f2bf(float f) {
  union { float f; unsigned u; } x; x.f = f;
  unsigned r = x.u + 0x7fffu + ((x.u >> 16) & 1u);   // RNE
  return (unsigned short)(r >> 16);
}

static __device__ __forceinline__ void gload16(const void* g, void* l) {
  __builtin_amdgcn_global_load_lds(
      (const __attribute__((address_space(1))) unsigned int*)g,
      (__attribute__((address_space(3))) unsigned int*)l,
      16, 0, 0);
}

// K1: fused prep. Blocks 0..15: pack label bits + colsum partials.
// Blocks 16..: fp32->bf16 conversion of X and Y (grid-stride).
__global__ void k_prep(const int* __restrict__ labels, unsigned* __restrict__ bits,
                       int* __restrict__ csPart,
                       const float* __restrict__ X, const float* __restrict__ Y,
                       unsigned short* __restrict__ Xb, unsigned short* __restrict__ Yb) {
  int t = threadIdx.x;
  if (blockIdx.x < 16) {
    __shared__ int cs[32];
    if (t < 32) cs[t] = 0;
    __syncthreads();
    int i = blockIdx.x * 256 + t;
    const int* row = labels + (size_t)i * 32;
    unsigned b = 0;
#pragma unroll
    for (int j = 0; j < 32; ++j) if (row[j] != 0) b |= (1u << j);
    bits[i] = b;
#pragma unroll
    for (int j = 0; j < 32; ++j) if (b & (1u << j)) atomicAdd(&cs[j], 1);
    __syncthreads();
    if (t < 32) csPart[blockIdx.x * 32 + t] = cs[t];
  } else {
    const int N4 = (NB * DK) / 4;  // 786432
    const int stride = (gridDim.x - 16) * 256;
    for (int idx = (blockIdx.x - 16) * 256 + t; idx < 2 * N4; idx += stride) {
      float4 v; unsigned short* dst;
      if (idx < N4) { v = ((const float4*)X)[idx]; dst = Xb + (size_t)idx * 4; }
      else          { v = ((const float4*)Y)[idx - N4]; dst = Yb + (size_t)(idx - N4) * 4; }
      uint2 p;
      p.x = (unsigned)f2bf(v.x) | ((unsigned)f2bf(v.y) << 16);
      p.y = (unsigned)f2bf(v.z) | ((unsigned)f2bf(v.w) << 16);
      *(uint2*)dst = p;
    }
  }
}

// K4: 256x256 bf16 MFMA GEMM — 8-phase m201-style template.
// BK=64, 12 K-tiles, 6 iters x 8 phases. 8 waves: wr=wave>>2 (128-row half),
// wc=wave&3 (64-col quarter); per-wave out 128x64 = acc[8][4].
// LDS: buf b (64KB): A[256 rows][128B] at b*65536, B at +32768.
// Swizzle: LDS[row][x] holds element (row, x ^ ((row&7)<<4)) — read applies the
// same XOR; stage pre-swizzles the GLOBAL source (linear LDS dest, rule #21).
// Stage units = 16KB row-halves. Region lifetimes (tile in buf): B-halves free
// after phase0 (B fully register-cached), A-halves after phase3. One unit staged
// per phase at earliest-free; vmcnt(4) before the end-barrier of phases 3 & 7.

#define STAGEU(DBUF, ISB, H, KT) do { \
    char* _lb = lds + (DBUF) * 65536 + (ISB) * 32768 + (H) * 16384 + wave * 1024; \
    const unsigned short* _g = ((ISB) ? pB : pA) + (size_t)(H) * 128 * DK + (size_t)(KT) * 64; \
    gload16(_g, _lb); \
    gload16(_g + (size_t)64 * DK, _lb + 8192); \
  } while (0)

#define PH(BUF, M0, LOADB, STAGES, WAITS) do { \
    const char* _c = lds + (BUF) * 65536; \
    if (LOADB) { \
      _Pragma("unroll") for (int n = 0; n < 4; ++n) { \
        bB[n][0] = *(const bf16x8*)(_c + 32768 + rowB0 + n * 2048 + offk0); \
        bB[n][1] = *(const bf16x8*)(_c + 32768 + rowB0 + n * 2048 + offk1); \
      } \
    } \
    bf16x8 _a00 = *(const bf16x8*)(_c + rowA0 + (M0) * 2048 + offk0); \
    bf16x8 _a01 = *(const bf16x8*)(_c + rowA0 + (M0) * 2048 + offk1); \
    bf16x8 _a10 = *(const bf16x8*)(_c + rowA0 + ((M0) + 1) * 2048 + offk0); \
    bf16x8 _a11 = *(const bf16x8*)(_c + rowA0 + ((M0) + 1) * 2048 + offk1); \
    STAGES \
    __builtin_amdgcn_s_barrier(); \
    asm volatile("s_waitcnt lgkmcnt(0)" ::: "memory"); \
    __builtin_amdgcn_sched_barrier(0); \
    __builtin_amdgcn_s_setprio(1); \
    _Pragma("unroll") for (int n = 0; n < 4; ++n) { \
      acc[(M0)][n]     = __builtin_amdgcn_mfma_f32_16x16x32_bf16(_a00, bB[n][0], acc[(M0)][n], 0, 0, 0); \
      acc[(M0)][n]     = __builtin_amdgcn_mfma_f32_16x16x32_bf16(_a01, bB[n][1], acc[(M0)][n], 0, 0, 0); \
      acc[(M0) + 1][n] = __builtin_amdgcn_mfma_f32_16x16x32_bf16(_a10, bB[n][0], acc[(M0) + 1][n], 0, 0, 0); \
      acc[(M0) + 1][n] = __builtin_amdgcn_mfma_f32_16x16x32_bf16(_a11, bB[n][1], acc[(M0) + 1][n], 0, 0, 0); \
    } \
    __builtin_amdgcn_s_setprio(0); \
    WAITS \
    __builtin_amdgcn_s_barrier(); \
  } while (0)

__launch_bounds__(512, 2)
__global__ void k_gemm(const unsigned short* __restrict__ Xb,
                       const unsigned short* __restrict__ Yb,
                       const unsigned* __restrict__ bits,
                       float* __restrict__ rowPM, float* __restrict__ rowPS,
                       float* __restrict__ colPM, float* __restrict__ colPS,
                       float* __restrict__ dotPart) {
  extern __shared__ char lds[];

  const int t = threadIdx.x;             // 0..511
  const int wave = t >> 6, lane = t & 63;
  const int wr = wave >> 2, wc = wave & 3;

  // bijective XCD-aware swizzle: each XCD gets a 4rb x 8cb sub-grid (16x16 grid)
  const int bid = blockIdx.x;
  const int xcd = bid & 7, loc = bid >> 3;
  const int rb = (xcd & 3) * 4 + (loc >> 3);
  const int cb = (xcd >> 2) * 8 + (loc & 7);

  // staging source pointers (pre-swizzled global column chunk per lane)
  const int laneSw8 = ((lane & 7) ^ (lane >> 3)) * 8;   // elements
  const unsigned short* pA = Xb + (size_t)(rb * 256 + wave * 8 + (lane >> 3)) * DK + laneSw8;
  const unsigned short* pB = Yb + (size_t)(cb * 256 + wave * 8 + (lane >> 3)) * DK + laneSw8;

  // fragment read offsets (bytes)
  const int swz = (lane & 7) << 4;
  const int offk0 = ((lane >> 4) * 16) ^ swz;
  const int offk1 = (64 + (lane >> 4) * 16) ^ swz;
  const int rowA0 = (wr * 128 + (lane & 15)) * 128;      // + m*2048
  const int rowB0 = (wc * 64 + (lane & 15)) * 128;       // + n*2048

  f32x4 acc[8][4];
#pragma unroll
  for (int m = 0; m < 8; ++m)
#pragma unroll
    for (int n = 0; n < 4; ++n) acc[m][n] = (f32x4){0.f, 0.f, 0.f, 0.f};

  bf16x8 bB[4][2];

  // prologue: t0 {B0,B1,A0,A1}, t1 {B0,B1}; wait all of t0 (leave t1's 2 units)
  STAGEU(0, 1, 0, 0); STAGEU(0, 1, 1, 0); STAGEU(0, 0, 0, 0); STAGEU(0, 0, 1, 0);
  STAGEU(1, 1, 0, 1); STAGEU(1, 1, 1, 1);
  asm volatile("s_waitcnt vmcnt(4)" ::: "memory");
  __builtin_amdgcn_s_barrier();

#pragma unroll 1
  for (int i = 0; i < 6; ++i) {
    const int O = 2 * i + 1;
    const bool g = (i < 5);
    // phases 0-3: compute tile E=2i (buf0)
    PH(0, 0, 1, { STAGEU(1, 0, 0, O); }, {});
    PH(0, 2, 0, { STAGEU(1, 0, 1, O); if (g) STAGEU(0, 1, 0, O + 1); }, {});
    PH(0, 4, 0, { if (g) STAGEU(0, 1, 1, O + 1); }, {});
    PH(0, 6, 0, {}, {
      if (i == 5) { asm volatile("s_waitcnt vmcnt(0)" ::: "memory"); }
      else        { asm volatile("s_waitcnt vmcnt(4)" ::: "memory"); }
    });
    // phases 4-7: compute tile O=2i+1 (buf1)
    PH(1, 0, 1, { if (g) STAGEU(0, 0, 0, O + 1); }, {});
    PH(1, 2, 0, { if (g) STAGEU(0, 0, 1, O + 1); }, {});
    PH(1, 4, 0, { if (g) STAGEU(1, 1, 0, O + 2); }, {});
    PH(1, 6, 0, { if (g) STAGEU(1, 1, 1, O + 2); }, {
      asm volatile("s_waitcnt vmcnt(4)" ::: "memory");
    });
  }
  __syncthreads();   // all LDS traffic done before reuse as reduction scratch

  // ---- epilogue ----
  // LDS scratch (floats): redM[256][4] | redS[256][4] | redM2[256][2] | redS2[256][2]
  //   | bR[256] u32 | bC[256] u32 | wred[8]
  float* fb    = (float*)lds;
  float* redM  = fb;                       // 1024
  float* redS  = fb + 1024;                // 1024
  float* redM2 = fb + 2048;                // 512
  float* redS2 = fb + 2560;                // 512
  unsigned* bR = (unsigned*)(fb + 3072);   // 256
  unsigned* bC = bR + 256;                 // 256
  float* wred  = (float*)(bC + 256);       // 8

  if (t < 256) bR[t] = bits[rb * 256 + t];
  else         bC[t - 256] = bits[cb * 256 + (t - 256)];

  // (a) row partials. C/D layout: col = lane&15, row = (lane>>4)*4 + reg [m89/m91]
#pragma unroll
  for (int m = 0; m < 8; ++m) {
#pragma unroll
    for (int r = 0; r < 4; ++r) {
      float v0 = SCALE_S * acc[m][0][r];
      float v1 = SCALE_S * acc[m][1][r];
      float v2 = SCALE_S * acc[m][2][r];
      float v3 = SCALE_S * acc[m][3][r];
      float mx = fmaxf(fmaxf(v0, v1), fmaxf(v2, v3));
#pragma unroll
      for (int off = 1; off < 16; off <<= 1) mx = fmaxf(mx, __shfl_xor(mx, off));
      float sm = __expf(v0 - mx) + __expf(v1 - mx) + __expf(v2 - mx) + __expf(v3 - mx);
#pragma unroll
      for (int off = 1; off < 16; off <<= 1) sm += __shfl_xor(sm, off);
      if ((lane & 15) == 0) {
        int row = wr * 128 + m * 16 + (lane >> 4) * 4 + r;
        redM[row * 4 + wc] = mx; redS[row * 4 + wc] = sm;
      }
    }
  }
  // col partials
#pragma unroll
  for (int n = 0; n < 4; ++n) {
    float mx = -3.0e38f;
#pragma unroll
    for (int m = 0; m < 8; ++m)
#pragma unroll
      for (int r = 0; r < 4; ++r) mx = fmaxf(mx, SCALE_S * acc[m][n][r]);
    mx = fmaxf(mx, __shfl_xor(mx, 16));
    mx = fmaxf(mx, __shfl_xor(mx, 32));
    float sm = 0.f;
#pragma unroll
    for (int m = 0; m < 8; ++m)
#pragma unroll
      for (int r = 0; r < 4; ++r) sm += __expf(SCALE_S * acc[m][n][r] - mx);
    sm += __shfl_xor(sm, 16);
    sm += __shfl_xor(sm, 32);
    if (lane < 16) {
      int col = wc * 64 + n * 16 + lane;
      redM2[col * 2 + wr] = mx; redS2[col * 2 + wr] = sm;
    }
  }
  __syncthreads();

  // (b) W.C tile sum: popcount(bits_row & bits_col) * C (unscaled)
  float ws = 0.f;
  {
    unsigned bc[4];
#pragma unroll
    for (int n = 0; n < 4; ++n) bc[n] = bC[wc * 64 + n * 16 + (lane & 15)];
#pragma unroll
    for (int m = 0; m < 8; ++m) {
#pragma unroll
      for (int r = 0; r < 4; ++r) {
        unsigned br = bR[wr * 128 + m * 16 + (lane >> 4) * 4 + r];
#pragma unroll
        for (int n = 0; n < 4; ++n)
          ws += (float)__popc(br & bc[n]) * acc[m][n][r];
      }
    }
  }
#pragma unroll
  for (int off = 32; off; off >>= 1) ws += __shfl_xor(ws, off);
  if (lane == 0) wred[wave] = ws;

  // combine partials -> per-(block,row/col) (M,S)
  if (t < 256) {
    float M = fmaxf(fmaxf(redM[t * 4 + 0], redM[t * 4 + 1]),
                    fmaxf(redM[t * 4 + 2], redM[t * 4 + 3]));
    float S = 0.f;
#pragma unroll
    for (int k = 0; k < 4; ++k) S += redS[t * 4 + k] * __expf(redM[t * 4 + k] - M);
    rowPM[(size_t)cb * NB + rb * 256 + t] = M;
    rowPS[(size_t)cb * NB + rb * 256 + t] = S;
  } else {
    int c = t - 256;
    float m0 = redM2[c * 2 + 0], m1 = redM2[c * 2 + 1];
    float M = fmaxf(m0, m1);
    float S = redS2[c * 2 + 0] * __expf(m0 - M) + redS2[c * 2 + 1] * __expf(m1 - M);
    colPM[(size_t)rb * NB + cb * 256 + c] = M;
    colPS[(size_t)rb * NB + cb * 256 + c] = S;
  }
  __syncthreads();
  if (t == 0) {
    float s = 0.f;
#pragma unroll
    for (int w = 0; w < 8; ++w) s += wred[w];
    dotPart[bid] = s;
  }
}

// K5: combine 16 lse partials per row/col AND fold in the rw-weighted sum
__global__ void k_tail(const float* __restrict__ rowPM, const float* __restrict__ rowPS,
                       const float* __restrict__ colPM, const float* __restrict__ colPS,
                       const unsigned* __restrict__ bits, const int* __restrict__ csPart,
                       float* __restrict__ wsum) {
  __shared__ int cs[32];
  __shared__ float red[256];
  int t = threadIdx.x, b = blockIdx.x;
  if (t < 32) {
    int s = 0;
    for (int k = 0; k < 16; ++k) s += csPart[k * 32 + t];
    cs[t] = s;
  }
  __syncthreads();
  int g = b * 256 + t;   // 0..8191
  int i; float M = -3.0e38f, S = 0.f;
  if (g < NB) {
    i = g;
#pragma unroll
    for (int c = 0; c < 16; ++c) M = fmaxf(M, rowPM[(size_t)c * NB + i]);
#pragma unroll
    for (int c = 0; c < 16; ++c) S += rowPS[(size_t)c * NB + i] * __expf(rowPM[(size_t)c * NB + i] - M);
  } else {
    i = g - NB;
#pragma unroll
    for (int c = 0; c < 16; ++c) M = fmaxf(M, colPM[(size_t)c * NB + i]);
#pragma unroll
    for (int c = 0; c < 16; ++c) S += colPS[(size_t)c * NB + i] * __expf(colPM[(size_t)c * NB + i] - M);
  }
  float lse = M + __logf(S);
  unsigned bb = bits[i];
  int rw = 0;
#pragma unroll
  for (int j = 0; j < 32; ++j) if (bb & (1u << j)) rw += cs[j];
  red[t] = (float)rw * lse;
  __syncthreads();
  for (int s = 128; s; s >>= 1) {
    if (t < s) red[t] += red[t + s];
    __syncthreads();
  }
  if (t == 0) wsum[b] = red[0];
}

// K7: finalize scalar loss from 32 wsum + 256 dot partials
__global__ void k_final(const float* __restrict__ wsum, const float* __restrict__ dotPart,
                        float* __restrict__ out) {
  __shared__ double red[256];
  int t = threadIdx.x;
  double a = 0.0;
  if (t < 32) a += (double)wsum[t];
  a -= 2.0 * (double)SCALE_S * (double)dotPart[t];
  red[t] = a;
  __syncthreads();
  for (int s = 128; s; s >>= 1) {
    if (t < s) red[t] += red[t + s];
    __syncthreads();
  }
  if (t == 0) out[0] = (float)(red[0] / (2.0 * (double)NB * 32.0));
}

extern "C" void kernel_launch(void* const* d_in, const int* in_sizes, int n_in,
                              void* d_out, int out_size, void* d_ws, size_t ws_size,
                              hipStream_t stream) {
  const float* X = (const float*)d_in[0];
  const float* Y = (const float*)d_in[1];
  const int* labels = (const int*)d_in[2];
  char* ws = (char*)d_ws;

  unsigned short* Xb = (unsigned short*)(ws + OFF_XB);
  unsigned short* Yb = (unsigned short*)(ws + OFF_YB);
  float* rowPM = (float*)(ws + OFF_ROWPM);
  float* rowPS = (float*)(ws + OFF_ROWPS);
  float* colPM = (float*)(ws + OFF_COLPM);
  float* colPS = (float*)(ws + OFF_COLPS);
  unsigned* bits = (unsigned*)(ws + OFF_BITS);
  int* csPart = (int*)(ws + OFF_CSPART);
  float* dotPart = (float*)(ws + OFF_DOTP);
  float* wsum = (float*)(ws + OFF_WSUM);

  // allow 128KB dynamic LDS for k_gemm (idempotent; ignore error)
  (void)hipFuncSetAttribute((const void*)k_gemm,
                            hipFuncAttributeMaxDynamicSharedMemorySize, 131072);

  k_prep<<<528, 256, 0, stream>>>(labels, bits, csPart, X, Y, Xb, Yb);
  k_gemm<<<256, 512, 131072, stream>>>(Xb, Yb, bits, rowPM, rowPS, colPM, colPS, dotPart);
  k_tail<<<32, 256, 0, stream>>>(rowPM, rowPS, colPM, colPS, bits, csPart, wsum);
  k_final<<<1, 256, 0, stream>>>(wsum, dotPart, (float*)d_out);
}

// Round 10
// 55.563 us; speedup vs baseline: 1.8204x; 1.0007x over previous
//
#include <hip/hip_runtime.h>

#define NB 4096
#define DK 768
#define SCALE_S 0.5295756522f

typedef float f32x4 __attribute__((ext_vector_type(4)));
typedef __bf16 bf16x8 __attribute__((ext_vector_type(8)));

// ---- ws layout (bytes) ----
#define OFF_XB      0u            // 4096*768 bf16 = 6291456
#define OFF_YB      6291456u
#define OFF_ROWPM   12582912u     // 16*4096 f32 (region reserved 512KB)
#define OFF_ROWPS   13107200u
#define OFF_COLPM   13631488u
#define OFF_COLPS   14155776u
#define OFF_BITS    14712832u     // 4096 u32
#define OFF_CSPART  14729216u     // 16*32 int
#define OFF_DOTP    14731264u     // 256 f32
#define OFF_WSUM    14732288u     // 32 f32

static __device__ __forceinline__ unsigned short f2bf(float f) {
  union { float f; unsigned u; } x; x.f = f;
  unsigned r = x.u + 0x7fffu + ((x.u >> 16) & 1u);   // RNE
  return (unsigned short)(r >> 16);
}

static __device__ __forceinline__ void gload16(const void* g, void* l) {
  __builtin_amdgcn_global_load_lds(
      (const __attribute__((address_space(1))) unsigned int*)g,
      (__attribute__((address_space(3))) unsigned int*)l,
      16, 0, 0);
}

// K1: fused prep. Blocks 0..15: pack label bits + colsum partials.
// Blocks 16..: fp32->bf16 conversion of X and Y (grid-stride).
__global__ void k_prep(const int* __restrict__ labels, unsigned* __restrict__ bits,
                       int* __restrict__ csPart,
                       const float* __restrict__ X, const float* __restrict__ Y,
                       unsigned short* __restrict__ Xb, unsigned short* __restrict__ Yb) {
  int t = threadIdx.x;
  if (blockIdx.x < 16) {
    __shared__ int cs[32];
    if (t < 32) cs[t] = 0;
    __syncthreads();
    int i = blockIdx.x * 256 + t;
    const int* row = labels + (size_t)i * 32;
    unsigned b = 0;
#pragma unroll
    for (int j = 0; j < 32; ++j) if (row[j] != 0) b |= (1u << j);
    bits[i] = b;
#pragma unroll
    for (int j = 0; j < 32; ++j) if (b & (1u << j)) atomicAdd(&cs[j], 1);
    __syncthreads();
    if (t < 32) csPart[blockIdx.x * 32 + t] = cs[t];
  } else {
    const int N4 = (NB * DK) / 4;  // 786432
    const int stride = (gridDim.x - 16) * 256;
    for (int idx = (blockIdx.x - 16) * 256 + t; idx < 2 * N4; idx += stride) {
      float4 v; unsigned short* dst;
      if (idx < N4) { v = ((const float4*)X)[idx]; dst = Xb + (size_t)idx * 4; }
      else          { v = ((const float4*)Y)[idx - N4]; dst = Yb + (size_t)(idx - N4) * 4; }
      uint2 p;
      p.x = (unsigned)f2bf(v.x) | ((unsigned)f2bf(v.y) << 16);
      p.y = (unsigned)f2bf(v.z) | ((unsigned)f2bf(v.w) << 16);
      *(uint2*)dst = p;
    }
  }
}

// K4: 256x256 bf16 MFMA GEMM. BK=64 (12 K-tiles), 2x64KB LDS double-buffer,
// depth-1 prefetch, ONE compiler-scheduled body per tile (fine-grained lgkmcnt,
// LDS reads overlap MFMA across waves), __syncthreads() drain per tile (issue-to
// -drain = full body >> HBM latency), conflict-free 8-row XOR swizzle (verified
// R9), setprio around MFMA, fused row/col (max,sumexp) + popcount W.C epilogue.
// LDS buf b (64KB): A[256r][128B] at b*65536, B at +32768.
// Swizzle: LDS[row][x] holds elem (row, x ^ ((row&7)<<4)); stage pre-swizzles
// the GLOBAL source (linear LDS dest, rule #21); reads apply the same XOR.

#define STAGEU(DBUF, ISB, H, KT) do { \
    char* _lb = lds + (DBUF) * 65536 + (ISB) * 32768 + (H) * 16384 + wave * 1024; \
    const unsigned short* _g = ((ISB) ? pB : pA) + (size_t)(H) * 128 * DK + (size_t)(KT) * 64; \
    gload16(_g, _lb); \
    gload16(_g + (size_t)64 * DK, _lb + 8192); \
  } while (0)

#define STAGE_T(DBUF, KT) do { \
    STAGEU(DBUF, 0, 0, KT); STAGEU(DBUF, 0, 1, KT); \
    STAGEU(DBUF, 1, 0, KT); STAGEU(DBUF, 1, 1, KT); \
  } while (0)

__launch_bounds__(512, 2)
__global__ void k_gemm(const unsigned short* __restrict__ Xb,
                       const unsigned short* __restrict__ Yb,
                       const unsigned* __restrict__ bits,
                       float* __restrict__ rowPM, float* __restrict__ rowPS,
                       float* __restrict__ colPM, float* __restrict__ colPS,
                       float* __restrict__ dotPart) {
  extern __shared__ char lds[];

  const int t = threadIdx.x;             // 0..511
  const int wave = t >> 6, lane = t & 63;
  const int wr = wave >> 2, wc = wave & 3;

  // bijective XCD-aware swizzle: each XCD gets a 4rb x 8cb sub-grid (16x16 grid)
  const int bid = blockIdx.x;
  const int xcd = bid & 7, loc = bid >> 3;
  const int rb = (xcd & 3) * 4 + (loc >> 3);
  const int cb = (xcd >> 2) * 8 + (loc & 7);

  // staging source pointers (pre-swizzled global column chunk per lane)
  const int laneSw8 = ((lane & 7) ^ (lane >> 3)) * 8;   // elements
  const unsigned short* pA = Xb + (size_t)(rb * 256 + wave * 8 + (lane >> 3)) * DK + laneSw8;
  const unsigned short* pB = Yb + (size_t)(cb * 256 + wave * 8 + (lane >> 3)) * DK + laneSw8;

  // fragment read offsets (bytes)
  const int swz = (lane & 7) << 4;
  const int offk0 = ((lane >> 4) * 16) ^ swz;
  const int offk1 = (64 + (lane >> 4) * 16) ^ swz;
  const int rowA0 = (wr * 128 + (lane & 15)) * 128;      // + m*2048
  const int rowB0 = (wc * 64 + (lane & 15)) * 128;       // + n*2048

  f32x4 acc[8][4];
#pragma unroll
  for (int m = 0; m < 8; ++m)
#pragma unroll
    for (int n = 0; n < 4; ++n) acc[m][n] = (f32x4){0.f, 0.f, 0.f, 0.f};

  // prologue: stage tile0 into buf0, wait, barrier
  STAGE_T(0, 0);
  asm volatile("s_waitcnt vmcnt(0)" ::: "memory");
  __builtin_amdgcn_s_barrier();

#pragma unroll 1
  for (int kt = 0; kt < 12; ++kt) {
    const int cur = kt & 1;
    if (kt < 11) {
      if (cur) STAGE_T(0, kt + 1); else STAGE_T(1, kt + 1);
    }
    const char* _c = lds + cur * 65536;
    bf16x8 bB[4][2];
#pragma unroll
    for (int n = 0; n < 4; ++n) {
      bB[n][0] = *(const bf16x8*)(_c + 32768 + rowB0 + n * 2048 + offk0);
      bB[n][1] = *(const bf16x8*)(_c + 32768 + rowB0 + n * 2048 + offk1);
    }
    __builtin_amdgcn_s_setprio(1);
#pragma unroll
    for (int m2 = 0; m2 < 4; ++m2) {
      bf16x8 a00 = *(const bf16x8*)(_c + rowA0 + (2 * m2) * 2048 + offk0);
      bf16x8 a01 = *(const bf16x8*)(_c + rowA0 + (2 * m2) * 2048 + offk1);
      bf16x8 a10 = *(const bf16x8*)(_c + rowA0 + (2 * m2 + 1) * 2048 + offk0);
      bf16x8 a11 = *(const bf16x8*)(_c + rowA0 + (2 * m2 + 1) * 2048 + offk1);
#pragma unroll
      for (int n = 0; n < 4; ++n) {
        acc[2 * m2][n]     = __builtin_amdgcn_mfma_f32_16x16x32_bf16(a00, bB[n][0], acc[2 * m2][n], 0, 0, 0);
        acc[2 * m2][n]     = __builtin_amdgcn_mfma_f32_16x16x32_bf16(a01, bB[n][1], acc[2 * m2][n], 0, 0, 0);
        acc[2 * m2 + 1][n] = __builtin_amdgcn_mfma_f32_16x16x32_bf16(a10, bB[n][0], acc[2 * m2 + 1][n], 0, 0, 0);
        acc[2 * m2 + 1][n] = __builtin_amdgcn_mfma_f32_16x16x32_bf16(a11, bB[n][1], acc[2 * m2 + 1][n], 0, 0, 0);
      }
    }
    __builtin_amdgcn_s_setprio(0);
    __syncthreads();   // drains vmcnt(0)+lgkmcnt(0): tile kt+1 landed, buf safe
  }

  // ---- epilogue ----
  // LDS scratch (floats): redM[256][4] | redS[256][4] | redM2[256][2] | redS2[256][2]
  //   | bR[256] u32 | bC[256] u32 | wred[8]
  float* fb    = (float*)lds;
  float* redM  = fb;                       // 1024
  float* redS  = fb + 1024;                // 1024
  float* redM2 = fb + 2048;                // 512
  float* redS2 = fb + 2560;                // 512
  unsigned* bR = (unsigned*)(fb + 3072);   // 256
  unsigned* bC = bR + 256;                 // 256
  float* wred  = (float*)(bC + 256);       // 8

  if (t < 256) bR[t] = bits[rb * 256 + t];
  else         bC[t - 256] = bits[cb * 256 + (t - 256)];

  // (a) row partials. C/D layout: col = lane&15, row = (lane>>4)*4 + reg [m89/m91]
#pragma unroll
  for (int m = 0; m < 8; ++m) {
#pragma unroll
    for (int r = 0; r < 4; ++r) {
      float v0 = SCALE_S * acc[m][0][r];
      float v1 = SCALE_S * acc[m][1][r];
      float v2 = SCALE_S * acc[m][2][r];
      float v3 = SCALE_S * acc[m][3][r];
      float mx = fmaxf(fmaxf(v0, v1), fmaxf(v2, v3));
#pragma unroll
      for (int off = 1; off < 16; off <<= 1) mx = fmaxf(mx, __shfl_xor(mx, off));
      float sm = __expf(v0 - mx) + __expf(v1 - mx) + __expf(v2 - mx) + __expf(v3 - mx);
#pragma unroll
      for (int off = 1; off < 16; off <<= 1) sm += __shfl_xor(sm, off);
      if ((lane & 15) == 0) {
        int row = wr * 128 + m * 16 + (lane >> 4) * 4 + r;
        redM[row * 4 + wc] = mx; redS[row * 4 + wc] = sm;
      }
    }
  }
  // col partials
#pragma unroll
  for (int n = 0; n < 4; ++n) {
    float mx = -3.0e38f;
#pragma unroll
    for (int m = 0; m < 8; ++m)
#pragma unroll
      for (int r = 0; r < 4; ++r) mx = fmaxf(mx, SCALE_S * acc[m][n][r]);
    mx = fmaxf(mx, __shfl_xor(mx, 16));
    mx = fmaxf(mx, __shfl_xor(mx, 32));
    float sm = 0.f;
#pragma unroll
    for (int m = 0; m < 8; ++m)
#pragma unroll
      for (int r = 0; r < 4; ++r) sm += __expf(SCALE_S * acc[m][n][r] - mx);
    sm += __shfl_xor(sm, 16);
    sm += __shfl_xor(sm, 32);
    if (lane < 16) {
      int col = wc * 64 + n * 16 + lane;
      redM2[col * 2 + wr] = mx; redS2[col * 2 + wr] = sm;
    }
  }
  __syncthreads();

  // (b) W.C tile sum: popcount(bits_row & bits_col) * C (unscaled)
  float ws = 0.f;
  {
    unsigned bc[4];
#pragma unroll
    for (int n = 0; n < 4; ++n) bc[n] = bC[wc * 64 + n * 16 + (lane & 15)];
#pragma unroll
    for (int m = 0; m < 8; ++m) {
#pragma unroll
      for (int r = 0; r < 4; ++r) {
        unsigned br = bR[wr * 128 + m * 16 + (lane >> 4) * 4 + r];
#pragma unroll
        for (int n = 0; n < 4; ++n)
          ws += (float)__popc(br & bc[n]) * acc[m][n][r];
      }
    }
  }
#pragma unroll
  for (int off = 32; off; off >>= 1) ws += __shfl_xor(ws, off);
  if (lane == 0) wred[wave] = ws;

  // combine partials -> per-(block,row/col) (M,S)
  if (t < 256) {
    float M = fmaxf(fmaxf(redM[t * 4 + 0], redM[t * 4 + 1]),
                    fmaxf(redM[t * 4 + 2], redM[t * 4 + 3]));
    float S = 0.f;
#pragma unroll
    for (int k = 0; k < 4; ++k) S += redS[t * 4 + k] * __expf(redM[t * 4 + k] - M);
    rowPM[(size_t)cb * NB + rb * 256 + t] = M;
    rowPS[(size_t)cb * NB + rb * 256 + t] = S;
  } else {
    int c = t - 256;
    float m0 = redM2[c * 2 + 0], m1 = redM2[c * 2 + 1];
    float M = fmaxf(m0, m1);
    float S = redS2[c * 2 + 0] * __expf(m0 - M) + redS2[c * 2 + 1] * __expf(m1 - M);
    colPM[(size_t)rb * NB + cb * 256 + c] = M;
    colPS[(size_t)rb * NB + cb * 256 + c] = S;
  }
  __syncthreads();
  if (t == 0) {
    float s = 0.f;
#pragma unroll
    for (int w = 0; w < 8; ++w) s += wred[w];
    dotPart[bid] = s;
  }
}

// K5: combine 16 lse partials per row/col AND fold in the rw-weighted sum
__global__ void k_tail(const float* __restrict__ rowPM, const float* __restrict__ rowPS,
                       const float* __restrict__ colPM, const float* __restrict__ colPS,
                       const unsigned* __restrict__ bits, const int* __restrict__ csPart,
                       float* __restrict__ wsum) {
  __shared__ int cs[32];
  __shared__ float red[256];
  int t = threadIdx.x, b = blockIdx.x;
  if (t < 32) {
    int s = 0;
    for (int k = 0; k < 16; ++k) s += csPart[k * 32 + t];
    cs[t] = s;
  }
  __syncthreads();
  int g = b * 256 + t;   // 0..8191
  int i; float M = -3.0e38f, S = 0.f;
  if (g < NB) {
    i = g;
#pragma unroll
    for (int c = 0; c < 16; ++c) M = fmaxf(M, rowPM[(size_t)c * NB + i]);
#pragma unroll
    for (int c = 0; c < 16; ++c) S += rowPS[(size_t)c * NB + i] * __expf(rowPM[(size_t)c * NB + i] - M);
  } else {
    i = g - NB;
#pragma unroll
    for (int c = 0; c < 16; ++c) M = fmaxf(M, colPM[(size_t)c * NB + i]);
#pragma unroll
    for (int c = 0; c < 16; ++c) S += colPS[(size_t)c * NB + i] * __expf(colPM[(size_t)c * NB + i] - M);
  }
  float lse = M + __logf(S);
  unsigned bb = bits[i];
  int rw = 0;
#pragma unroll
  for (int j = 0; j < 32; ++j) if (bb & (1u << j)) rw += cs[j];
  red[t] = (float)rw * lse;
  __syncthreads();
  for (int s = 128; s; s >>= 1) {
    if (t < s) red[t] += red[t + s];
    __syncthreads();
  }
  if (t == 0) wsum[b] = red[0];
}

// K7: finalize scalar loss from 32 wsum + 256 dot partials
__global__ void k_final(const float* __restrict__ wsum, const float* __restrict__ dotPart,
                        float* __restrict__ out) {
  __shared__ double red[256];
  int t = threadIdx.x;
  double a = 0.0;
  if (t < 32) a += (double)wsum[t];
  a -= 2.0 * (double)SCALE_S * (double)dotPart[t];
  red[t] = a;
  __syncthreads();
  for (int s = 128; s; s >>= 1) {
    if (t < s) red[t] += red[t + s];
    __syncthreads();
  }
  if (t == 0) out[0] = (float)(red[0] / (2.0 * (double)NB * 32.0));
}

extern "C" void kernel_launch(void* const* d_in, const int* in_sizes, int n_in,
                              void* d_out, int out_size, void* d_ws, size_t ws_size,
                              hipStream_t stream) {
  const float* X = (const float*)d_in[0];
  const float* Y = (const float*)d_in[1];
  const int* labels = (const int*)d_in[2];
  char* ws = (char*)d_ws;

  unsigned short* Xb = (unsigned short*)(ws + OFF_XB);
  unsigned short* Yb = (unsigned short*)(ws + OFF_YB);
  float* rowPM = (float*)(ws + OFF_ROWPM);
  float* rowPS = (float*)(ws + OFF_ROWPS);
  float* colPM = (float*)(ws + OFF_COLPM);
  float* colPS = (float*)(ws + OFF_COLPS);
  unsigned* bits = (unsigned*)(ws + OFF_BITS);
  int* csPart = (int*)(ws + OFF_CSPART);
  float* dotPart = (float*)(ws + OFF_DOTP);
  float* wsum = (float*)(ws + OFF_WSUM);

  // allow 128KB dynamic LDS for k_gemm (idempotent; ignore error)
  (void)hipFuncSetAttribute((const void*)k_gemm,
                            hipFuncAttributeMaxDynamicSharedMemorySize, 131072);

  k_prep<<<528, 256, 0, stream>>>(labels, bits, csPart, X, Y, Xb, Yb);
  k_gemm<<<256, 512, 131072, stream>>>(Xb, Yb, bits, rowPM, rowPS, colPM, colPS, dotPart);
  k_tail<<<32, 256, 0, stream>>>(rowPM, rowPS, colPM, colPS, bits, csPart, wsum);
  k_final<<<1, 256, 0, stream>>>(wsum, dotPart, (float*)d_out);
}